// Round 4
// baseline (172.361 us; speedup 1.0000x reference)
//
#include <hip/hip_runtime.h>
#include <math.h>

#define PAD_ID 12975
#define BB 256
#define SS 200
#define DD 1024
#define HH 16

#define MASK_CHUNKS (BB * HH * SS * (SS / 4))   // 40,960,000 float4 chunks
#define OUT_ROWS    (BB * SS)                   // 51,200 rows of 1024 floats

#define NBLK 2048      // total blocks
#define MBLK 1280      // mask partition (655MB writes) vs out partition (~420MB + trig)

// clang vector types — __builtin_nontemporal_store needs true vector types.
typedef float f32x4 __attribute__((ext_vector_type(4)));
typedef int   i32x4 __attribute__((ext_vector_type(4)));

// Single fused kernel:
//   blocks [0, MBLK):    mask[b,h,i,j] = (x[b,j]==PAD) || (i >= first[b])
//                        first[] computed per-block in LDS (x is 204KB, L2-hot)
//   blocks [MBLK, NBLK): out[row,:] = weight[x[row],:] + sinusoid(row%S, :)
//                        sinusoid inline: per-thread denominators are loop-invariant
__global__ void work_kernel(const int* __restrict__ x, const float* __restrict__ weight,
                            float* __restrict__ out, float* __restrict__ mask) {
    if (blockIdx.x < MBLK) {
        // ---- per-block first[] build: thread t scans batch row t ----
        __shared__ int sfirst[BB];
        {
            const int t = threadIdx.x;           // 256 threads == BB rows
            int f = SS - 1;                      // no-pad => S-1 (reference semantics)
            const i32x4* xr = (const i32x4*)(x + t * SS);
            #pragma unroll 10
            for (int j4 = 49; j4 >= 0; --j4) {   // descending: min() keeps first hit
                const i32x4 v = xr[j4];
                const int base = j4 * 4;
                if (v.w == PAD_ID) f = base + 3 < f ? base + 3 : f;
                if (v.z == PAD_ID) f = base + 2 < f ? base + 2 : f;
                if (v.y == PAD_ID) f = base + 1 < f ? base + 1 : f;
                if (v.x == PAD_ID) f = base + 0 < f ? base + 0 : f;
            }
            sfirst[t] = f;
        }
        __syncthreads();
        // ---- streaming mask write ----
        const int stride = MBLK * 256;
        for (int c = blockIdx.x * 256 + threadIdx.x; c < MASK_CHUNKS; c += stride) {
            const int row = c / 50;              // 50 float4 per S=200 row
            const int j4  = c - row * 50;
            const int b   = row / (HH * SS);     // /3200
            const int i   = row % SS;
            f32x4 v;
            if (i >= sfirst[b]) {
                v = (f32x4){1.f, 1.f, 1.f, 1.f};
            } else {
                const i32x4 xv = ((const i32x4*)x)[b * 50 + j4];   // L2-hot
                v.x = (xv.x == PAD_ID) ? 1.f : 0.f;
                v.y = (xv.y == PAD_ID) ? 1.f : 0.f;
                v.z = (xv.z == PAD_ID) ? 1.f : 0.f;
                v.w = (xv.w == PAD_ID) ? 1.f : 0.f;
            }
            __builtin_nontemporal_store(v, (f32x4*)mask + c);
        }
    } else {
        // ---- embedding + inline sinusoid ----
        const int t = threadIdx.x;               // handles j = 4t..4t+3
        const float C = (float)(13.287712379549449 / 512.0);   // log2(10000)/512
        const float rd0 = exp2f(-(float)(2 * t) * C);          // 1/10000^(2t/512)
        const float rd1 = exp2f(-(float)(2 * t + 1) * C);      // 1/10000^((2t+1)/512)
        const int ob = blockIdx.x - MBLK;
        const int OB = NBLK - MBLK;
        for (int row = ob; row < OUT_ROWS; row += OB) {
            const int s   = row % SS;
            const int idx = x[row];              // block-uniform scalar load
            const float fs = (float)s;
            const float a0 = fs * rd0;
            const float a1 = fs * rd1;
            const f32x4 pe = (f32x4){sinf(a0), cosf(a0), sinf(a1), cosf(a1)};
            const f32x4 w = ((const f32x4*)(weight + (size_t)idx * DD))[t];
            __builtin_nontemporal_store(w + pe, (f32x4*)(out + (size_t)row * DD) + t);
        }
    }
}

extern "C" void kernel_launch(void* const* d_in, const int* in_sizes, int n_in,
                              void* d_out, int out_size, void* d_ws, size_t ws_size,
                              hipStream_t stream) {
    const int*   x      = (const int*)d_in[0];
    const float* weight = (const float*)d_in[1];
    float* out  = (float*)d_out;
    float* mask = out + (size_t)BB * SS * DD;   // outputs concatenated: (out, mask)

    work_kernel<<<NBLK, 256, 0, stream>>>(x, weight, out, mask);
}